// Round 1
// baseline (6005.091 us; speedup 1.0000x reference)
//
#include <hip/hip_runtime.h>

typedef _Float16 half2_t __attribute__((ext_vector_type(2)));
typedef unsigned int u32;

#define BB 64
#define TT 2048
#define II 128
#define HH 256
#define CC 64
#define G3 (3*HH)          // 768
#define MTOT (BB*TT)       // 131072

static __device__ __forceinline__ float dot2f(half2_t a, half2_t b, float c) {
#if __has_builtin(__builtin_amdgcn_fdot2)
    return __builtin_amdgcn_fdot2(a, b, c, false);
#else
    return c + (float)a[0]*(float)b[0] + (float)a[1]*(float)b[1];
#endif
}

// ---------------------------------------------------------------------------
// Tiled GEMM: C[M,N] = A[M,K] @ W[N,K]^T + bias, f16 dot2 inner, fp32 accum.
// Tile 128(M) x 64(N), K-chunk 32. 256 threads, 8x4 micro-tile per thread.
// blockIdx.x = n-tile (fast) so consecutive blocks share the A m-tile in L2.
// ---------------------------------------------------------------------------
template<typename AT, typename CT>
__global__ __launch_bounds__(256, 2)
void gemm_bt(const AT* __restrict__ A, const float* __restrict__ W,
             const float* __restrict__ bias, CT* __restrict__ Cout,
             int M, int N, int K)
{
    __shared__ half2_t As[128][17];   // 16 k-pairs + 1 pad
    __shared__ half2_t Bs[64][17];
    const int tid = threadIdx.x;
    const int m0 = blockIdx.y * 128;
    const int n0 = blockIdx.x * 64;
    const int mt = tid & 15;          // 16 m-tiles of 8 rows
    const int nt = tid >> 4;          // 16 n-tiles of 4 cols
    float acc[8][4] = {};

    for (int kc = 0; kc < K; kc += 32) {
        {   // A tile: 128 rows x 32 k
            const int row = tid >> 1;
            const int ko  = (tid & 1) * 16;
            const AT* src = A + (size_t)(m0 + row) * K + kc + ko;
            #pragma unroll
            for (int u = 0; u < 8; ++u)
                As[row][(ko >> 1) + u] =
                    half2_t{(_Float16)(float)src[2*u], (_Float16)(float)src[2*u+1]};
        }
        {   // B tile: 64 rows x 32 k (weights, fp32 -> f16)
            const int row = tid >> 2;
            const int ko  = (tid & 3) * 8;
            const float* src = W + (size_t)(n0 + row) * K + kc + ko;
            #pragma unroll
            for (int u = 0; u < 4; ++u)
                Bs[row][(ko >> 1) + u] =
                    half2_t{(_Float16)src[2*u], (_Float16)src[2*u+1]};
        }
        __syncthreads();
        #pragma unroll
        for (int kp = 0; kp < 16; ++kp) {
            half2_t av[8], bv[4];
            #pragma unroll
            for (int r = 0; r < 8; ++r) av[r] = As[mt*8 + r][kp];
            #pragma unroll
            for (int c = 0; c < 4; ++c) bv[c] = Bs[nt*4 + c][kp];
            #pragma unroll
            for (int r = 0; r < 8; ++r)
                #pragma unroll
                for (int c = 0; c < 4; ++c)
                    acc[r][c] = dot2f(av[r], bv[c], acc[r][c]);
        }
        __syncthreads();
    }
    #pragma unroll
    for (int r = 0; r < 8; ++r) {
        const int m = m0 + mt*8 + r;
        #pragma unroll
        for (int c = 0; c < 4; ++c) {
            const int n = n0 + nt*4 + c;
            Cout[(size_t)m * N + n] = (CT)(acc[r][c] + bias[n]);
        }
    }
}

// ---------------------------------------------------------------------------
// Persistent GRU scan. One WG per batch element, 512 threads (8 waves).
// Thread t: row j = t>>1 (0..255), k-half kh = t&1. Holds W_hh rows
// {j, 256+j, 512+j} for its k-half as f16 pairs in VGPRs (192 regs).
// h (256 f16) lives in LDS; per step each thread reads its 128-value half
// via 16 ds_read_b128 (2 distinct addrs per wave -> broadcast, free),
// does 192 v_dot2_f32_f16, reduces the k-halves via shfl_xor(1), applies
// the GRU gate math, and threads t%4==0 write the packed new h to LDS +
// the layer output (f16, consumed by the next phase's GEMM).
// ---------------------------------------------------------------------------
__global__ __launch_bounds__(512, 2)
void gru_scan(const _Float16* __restrict__ gx,   // [B, T, 768] incl. b_ih
              const float* __restrict__ Whh,     // [768, 256]
              const float* __restrict__ bhh,     // [768]
              _Float16* __restrict__ hout)       // [B, T, 256]
{
    const int b  = blockIdx.x;
    const int t  = threadIdx.x;
    const int j  = t >> 1;
    const int kh = t & 1;

    half2_t w0[64], w1[64], w2[64];
    {
        const float* p0 = Whh + (size_t)j * HH + kh * 128;
        const float* p1 = p0 + 256 * HH;
        const float* p2 = p0 + 512 * HH;
        #pragma unroll
        for (int i = 0; i < 64; ++i) {
            w0[i] = half2_t{(_Float16)p0[2*i], (_Float16)p0[2*i+1]};
            w1[i] = half2_t{(_Float16)p1[2*i], (_Float16)p1[2*i+1]};
            w2[i] = half2_t{(_Float16)p2[2*i], (_Float16)p2[2*i+1]};
        }
    }
    const float bh_r = bhh[j], bh_z = bhh[HH + j], bh_n = bhh[2*HH + j];

    __shared__ alignas(16) u32 h2[HH/2];   // 256 f16 packed
    if (t < HH/2) h2[t] = 0u;
    float hprev = 0.f;
    __syncthreads();

    const _Float16* g = gx + (size_t)b * TT * G3;
    u32* op = (u32*)(hout + (size_t)b * TT * HH);

    for (int step = 0; step < TT; ++step) {
        // input-side gate preactivations (loads issue early, hidden by dots)
        float xr = (float)g[j];
        float xz = (float)g[HH + j];
        float xn = (float)g[2*HH + j];

        const uint4* hb = (const uint4*)(h2 + kh * 64);
        float ar = 0.f, az = 0.f, an = 0.f;
        #pragma unroll
        for (int c = 0; c < 16; ++c) {
            uint4 hv = hb[c];
            half2_t ha = __builtin_bit_cast(half2_t, hv.x);
            half2_t hc = __builtin_bit_cast(half2_t, hv.y);
            half2_t hd = __builtin_bit_cast(half2_t, hv.z);
            half2_t he = __builtin_bit_cast(half2_t, hv.w);
            ar = dot2f(ha, w0[4*c+0], ar); az = dot2f(ha, w1[4*c+0], az); an = dot2f(ha, w2[4*c+0], an);
            ar = dot2f(hc, w0[4*c+1], ar); az = dot2f(hc, w1[4*c+1], az); an = dot2f(hc, w2[4*c+1], an);
            ar = dot2f(hd, w0[4*c+2], ar); az = dot2f(hd, w1[4*c+2], az); an = dot2f(hd, w2[4*c+2], an);
            ar = dot2f(he, w0[4*c+3], ar); az = dot2f(he, w1[4*c+3], az); an = dot2f(he, w2[4*c+3], an);
        }
        // combine the two k-halves (partner lane = t^1, same wave)
        ar += __shfl_xor(ar, 1);
        az += __shfl_xor(az, 1);
        an += __shfl_xor(an, 1);

        const float r = 1.f / (1.f + __expf(-(xr + ar + bh_r)));
        const float z = 1.f / (1.f + __expf(-(xz + az + bh_z)));
        const float e = __expf(2.f * (xn + r * (an + bh_n)));
        const float n = 1.f - 2.f / (e + 1.f);
        const float hnew = (1.f - z) * n + z * hprev;
        hprev = hnew;

        const float hother = __shfl_xor(hnew, 2);   // row j^1 (lane t^2)
        __syncthreads();                             // all h2 reads done
        if ((t & 3) == 0) {                          // j even, kh 0: owns pair j/2
            half2_t hp{(_Float16)hnew, (_Float16)hother};
            const u32 pu = __builtin_bit_cast(u32, hp);
            h2[t >> 2] = pu;
            op[t >> 2] = pu;
        }
        __syncthreads();
        g  += G3;
        op += HH/2;
    }
}

// ---------------------------------------------------------------------------
extern "C" void kernel_launch(void* const* d_in, const int* in_sizes, int n_in,
                              void* d_out, int out_size, void* d_ws, size_t ws_size,
                              hipStream_t stream) {
    const float* x    = (const float*)d_in[0];
    const float* Wih0 = (const float*)d_in[1];
    const float* Whh0 = (const float*)d_in[2];
    const float* bih0 = (const float*)d_in[3];
    const float* bhh0 = (const float*)d_in[4];
    const float* Wih1 = (const float*)d_in[5];
    const float* Whh1 = (const float*)d_in[6];
    const float* bih1 = (const float*)d_in[7];
    const float* bhh1 = (const float*)d_in[8];
    const float* fcw  = (const float*)d_in[9];
    const float* fcb  = (const float*)d_in[10];
    float* out = (float*)d_out;

    // workspace: gx buffer (192 MB, reused for both layers) + h buffer (64 MB)
    _Float16* gxbuf = (_Float16*)d_ws;
    _Float16* hbuf  = (_Float16*)((char*)d_ws + (size_t)MTOT * G3 * sizeof(_Float16));

    const dim3 blk(256);
    // 1) gx0 = x @ W_ih0^T + b_ih0
    gemm_bt<float, _Float16><<<dim3(G3/64, MTOT/128), blk, 0, stream>>>(
        x, Wih0, bih0, gxbuf, MTOT, G3, II);
    // 2) scan layer 0 -> h0
    gru_scan<<<dim3(BB), dim3(512), 0, stream>>>(gxbuf, Whh0, bhh0, hbuf);
    // 3) gx1 = h0 @ W_ih1^T + b_ih1 (overwrites gx buffer)
    gemm_bt<_Float16, _Float16><<<dim3(G3/64, MTOT/128), blk, 0, stream>>>(
        hbuf, Wih1, bih1, gxbuf, MTOT, G3, HH);
    // 4) scan layer 1 -> h1 (overwrites h buffer)
    gru_scan<<<dim3(BB), dim3(512), 0, stream>>>(gxbuf, Whh1, bhh1, hbuf);
    // 5) out = h1 @ fc_w^T + fc_b
    gemm_bt<_Float16, float><<<dim3(CC/64, MTOT/128), blk, 0, stream>>>(
        hbuf, fcw, fcb, out, MTOT, CC, HH);
}